// Round 1
// baseline (2581.079 us; speedup 1.0000x reference)
//
#include <hip/hip_runtime.h>

// Problem constants (verified against in_sizes at launch where cheap).
#define CIN 32
#define COUT 64

// ---------------------------------------------------------------------------
// Transpose W2 [64][64] -> W2T [64][64] in ws so layer-2 reads are contiguous.
__global__ void w2_transpose_kernel(const float* __restrict__ W2,
                                    float* __restrict__ W2T) {
    int i = blockIdx.x * blockDim.x + threadIdx.x;   // 4096 threads
    if (i < COUT * COUT) {
        int j = i / COUT;   // row of W2
        int k = i % COUT;   // col of W2
        W2T[k * COUT + j] = W2[j * COUT + k];
    }
}

// ---------------------------------------------------------------------------
// new_bxyz = point_bxyz[sample_idx]  (float4 copy per sampled point)
__global__ void gather_bxyz_kernel(const float4* __restrict__ bxyz4,
                                   const int* __restrict__ sidx,
                                   float4* __restrict__ out4, int M) {
    int i = blockIdx.x * blockDim.x + threadIdx.x;
    if (i < M) out4[i] = bxyz4[sidx[i]];
}

// ---------------------------------------------------------------------------
// Zero the new_feat region (harness poisons 0xAA; we must init every call).
__global__ void zero_feat_kernel(float4* __restrict__ p, int n4) {
    int i = blockIdx.x * blockDim.x + threadIdx.x;
    if (i < n4) p[i] = make_float4(0.f, 0.f, 0.f, 0.f);
}

// ---------------------------------------------------------------------------
// Per-edge MLP + scatter-max. Lane = edge. All weight indices are wave-uniform
// -> scalar loads; FMAs run v_fmac_f32 v,s,v at full VALU rate.
__global__ __launch_bounds__(256)
void edge_kernel(const float4* __restrict__ bxyz4,
                 const float* __restrict__ feat,
                 const int* __restrict__ e_point,
                 const int* __restrict__ e_new,
                 const float* __restrict__ W1,   // [35][64] row-major
                 const float* __restrict__ b1,   // [64]
                 const float* __restrict__ W2T,  // [64][64] transposed
                 const float* __restrict__ b2,   // [64]
                 const float4* __restrict__ new_bxyz4,  // [M] (already gathered)
                 float* __restrict__ out_feat,   // [M][64], pre-zeroed
                 int E) {
    int e = blockIdx.x * blockDim.x + threadIdx.x;
    if (e >= E) return;

    int ep = e_point[e];
    int en = e_new[e];

    float4 pb = bxyz4[ep];
    float4 nb = new_bxyz4[en];
    float r0 = pb.y - nb.y;
    float r1 = pb.z - nb.z;
    float r2 = pb.w - nb.w;

    // ---- layer 1: h1[k] = relu(b1[k] + sum_j x[j]*W1[j][k]) ----------------
    float h1[COUT];
#pragma unroll
    for (int k = 0; k < COUT; ++k) h1[k] = b1[k];

    const float* frow = feat + (long long)ep * CIN;
    for (int j = 0; j < CIN; ++j) {          // rolled: small code, scalar W rows
        float x = frow[j];
#pragma unroll
        for (int k = 0; k < COUT; ++k)
            h1[k] = fmaf(x, W1[j * COUT + k], h1[k]);
    }
    {
        // rel-position terms (rows 32..34 of W1), compile-time unrolled
#pragma unroll
        for (int k = 0; k < COUT; ++k) h1[k] = fmaf(r0, W1[32 * COUT + k], h1[k]);
#pragma unroll
        for (int k = 0; k < COUT; ++k) h1[k] = fmaf(r1, W1[33 * COUT + k], h1[k]);
#pragma unroll
        for (int k = 0; k < COUT; ++k) h1[k] = fmaf(r2, W1[34 * COUT + k], h1[k]);
    }
#pragma unroll
    for (int k = 0; k < COUT; ++k) h1[k] = fmaxf(h1[k], 0.f);

    // ---- layer 2 + scatter-max --------------------------------------------
    // relu => h >= 0, so float bits compare correctly as signed int.
    int* outp = (int*)(out_feat + (long long)en * COUT);
    for (int k = 0; k < COUT; ++k) {         // rolled
        float h = b2[k];
#pragma unroll
        for (int j = 0; j < COUT; ++j)
            h = fmaf(h1[j], W2T[k * COUT + j], h);
        h = fmaxf(h, 0.f);
        int hb = __float_as_int(h);
        // pre-check: skip atomic when another edge already wrote >= h
        if (hb > outp[k]) atomicMax(&outp[k], hb);
    }
}

// ---------------------------------------------------------------------------
extern "C" void kernel_launch(void* const* d_in, const int* in_sizes, int n_in,
                              void* d_out, int out_size, void* d_ws, size_t ws_size,
                              hipStream_t stream) {
    const float* bxyz   = (const float*)d_in[0];
    const float* feat   = (const float*)d_in[1];
    const int*   sidx   = (const int*)d_in[2];
    const int*   e_pt   = (const int*)d_in[3];
    const int*   e_new  = (const int*)d_in[4];
    const float* W1     = (const float*)d_in[5];
    const float* b1     = (const float*)d_in[6];
    const float* W2     = (const float*)d_in[7];
    const float* b2     = (const float*)d_in[8];

    const int M = in_sizes[2];
    const int E = in_sizes[3];

    float* out_bxyz = (float*)d_out;                 // [M][4]
    float* out_feat = out_bxyz + (size_t)M * 4;      // [M][64]
    float* W2T      = (float*)d_ws;                  // 16 KiB scratch

    w2_transpose_kernel<<<(COUT * COUT + 255) / 256, 256, 0, stream>>>(W2, W2T);

    gather_bxyz_kernel<<<(M + 255) / 256, 256, 0, stream>>>(
        (const float4*)bxyz, sidx, (float4*)out_bxyz, M);

    int n4 = M * COUT / 4;
    zero_feat_kernel<<<(n4 + 255) / 256, 256, 0, stream>>>((float4*)out_feat, n4);

    edge_kernel<<<(E + 255) / 256, 256, 0, stream>>>(
        (const float4*)bxyz, feat, e_pt, e_new, W1, b1, W2T, b2,
        (const float4*)out_bxyz, out_feat, E);
}

// Round 2
// 1892.133 us; speedup vs baseline: 1.3641x; 1.3641x over previous
//
#include <hip/hip_runtime.h>

#define CIN 32
#define COUT 64

// ---------------------------------------------------------------------------
// Transpose W2 [64][64] -> W2T [64][64] in ws so layer-2 reads are contiguous.
__global__ void w2_transpose_kernel(const float* __restrict__ W2,
                                    float* __restrict__ W2T) {
    int i = blockIdx.x * blockDim.x + threadIdx.x;
    if (i < COUT * COUT) {
        int j = i / COUT;
        int k = i % COUT;
        W2T[k * COUT + j] = W2[j * COUT + k];
    }
}

// ---------------------------------------------------------------------------
// new_bxyz = point_bxyz[sample_idx]
__global__ void gather_bxyz_kernel(const float4* __restrict__ bxyz4,
                                   const int* __restrict__ sidx,
                                   float4* __restrict__ out4, int M) {
    int i = blockIdx.x * blockDim.x + threadIdx.x;
    if (i < M) out4[i] = bxyz4[sidx[i]];
}

// ---------------------------------------------------------------------------
__global__ void zero_feat_kernel(float4* __restrict__ p, int n4) {
    int i = blockIdx.x * blockDim.x + threadIdx.x;
    if (i < n4) p[i] = make_float4(0.f, 0.f, 0.f, 0.f);
}

// ---------------------------------------------------------------------------
// Per-edge MLP + scatter-max, lane = edge.
// All same-line global accesses are clustered into back-to-back vector loads
// so each 128B line is fetched ONCE per edge (R1 had them strewn across the
// compute loops -> every access was an independent L1/L2 miss -> 7.1 GB).
__global__ __launch_bounds__(256)
void edge_kernel(const float4* __restrict__ bxyz4,
                 const float* __restrict__ feat,
                 const int* __restrict__ e_point,
                 const int* __restrict__ e_new,
                 const float* __restrict__ W1,   // [35][64] row-major
                 const float* __restrict__ b1,   // [64]
                 const float* __restrict__ W2T,  // [64][64] transposed
                 const float* __restrict__ b2,   // [64]
                 const float4* __restrict__ new_bxyz4,  // [M]
                 float* __restrict__ out_feat,   // [M][64], pre-zeroed
                 int E) {
    int e = blockIdx.x * blockDim.x + threadIdx.x;
    if (e >= E) return;

    int ep = e_point[e];
    int en = e_new[e];

    // ---- clustered gathers: one clause per line --------------------------
    const float4* frow4 = (const float4*)(feat + (size_t)ep * CIN);
    float4 xv[8];
#pragma unroll
    for (int j4 = 0; j4 < 8; ++j4) xv[j4] = frow4[j4];   // one 128B line

    float4 pb = bxyz4[ep];
    float4 nb = new_bxyz4[en];
    float r0 = pb.y - nb.y;
    float r1 = pb.z - nb.z;
    float r2 = pb.w - nb.w;

    // ---- layer 1 ---------------------------------------------------------
    float h1[COUT];
#pragma unroll
    for (int k = 0; k < COUT; ++k) h1[k] = b1[k];

#pragma unroll
    for (int j4 = 0; j4 < 8; ++j4) {
        float xs0 = xv[j4].x, xs1 = xv[j4].y, xs2 = xv[j4].z, xs3 = xv[j4].w;
        int j = j4 * 4;
#pragma unroll
        for (int k = 0; k < COUT; ++k) h1[k] = fmaf(xs0, W1[(j + 0) * COUT + k], h1[k]);
#pragma unroll
        for (int k = 0; k < COUT; ++k) h1[k] = fmaf(xs1, W1[(j + 1) * COUT + k], h1[k]);
#pragma unroll
        for (int k = 0; k < COUT; ++k) h1[k] = fmaf(xs2, W1[(j + 2) * COUT + k], h1[k]);
#pragma unroll
        for (int k = 0; k < COUT; ++k) h1[k] = fmaf(xs3, W1[(j + 3) * COUT + k], h1[k]);
    }
#pragma unroll
    for (int k = 0; k < COUT; ++k) h1[k] = fmaf(r0, W1[32 * COUT + k], h1[k]);
#pragma unroll
    for (int k = 0; k < COUT; ++k) h1[k] = fmaf(r1, W1[33 * COUT + k], h1[k]);
#pragma unroll
    for (int k = 0; k < COUT; ++k) h1[k] = fmaf(r2, W1[34 * COUT + k], h1[k]);
#pragma unroll
    for (int k = 0; k < COUT; ++k) h1[k] = fmaxf(h1[k], 0.f);

    // ---- layer 2 (fully unrolled -> h2 in registers) ---------------------
    float h2[COUT];
#pragma unroll
    for (int k = 0; k < COUT; ++k) {
        float h = b2[k];
#pragma unroll
        for (int j = 0; j < COUT; ++j)
            h = fmaf(h1[j], W2T[k * COUT + j], h);
        h2[k] = fmaxf(h, 0.f);
    }

    // ---- scatter-max with clustered pre-check reads ----------------------
    // relu => h >= 0 so float bits compare correctly as signed int.
    // Two clusters of 8x int4 (one 128B line each), loads issued before the
    // corresponding atomics; stale reads are safe (values only grow).
    int* outp = (int*)(out_feat + (size_t)en * COUT);
    const int4* outp4 = (const int4*)outp;

#pragma unroll
    for (int half = 0; half < 2; ++half) {
        int4 o[8];
#pragma unroll
        for (int c = 0; c < 8; ++c) o[c] = outp4[half * 8 + c];
#pragma unroll
        for (int c = 0; c < 8; ++c) {
            int kbase = half * 32 + c * 4;
            int v0 = __float_as_int(h2[kbase + 0]);
            int v1 = __float_as_int(h2[kbase + 1]);
            int v2 = __float_as_int(h2[kbase + 2]);
            int v3 = __float_as_int(h2[kbase + 3]);
            if (v0 > o[c].x) atomicMax(&outp[kbase + 0], v0);
            if (v1 > o[c].y) atomicMax(&outp[kbase + 1], v1);
            if (v2 > o[c].z) atomicMax(&outp[kbase + 2], v2);
            if (v3 > o[c].w) atomicMax(&outp[kbase + 3], v3);
        }
    }
}

// ---------------------------------------------------------------------------
extern "C" void kernel_launch(void* const* d_in, const int* in_sizes, int n_in,
                              void* d_out, int out_size, void* d_ws, size_t ws_size,
                              hipStream_t stream) {
    const float* bxyz   = (const float*)d_in[0];
    const float* feat   = (const float*)d_in[1];
    const int*   sidx   = (const int*)d_in[2];
    const int*   e_pt   = (const int*)d_in[3];
    const int*   e_new  = (const int*)d_in[4];
    const float* W1     = (const float*)d_in[5];
    const float* b1     = (const float*)d_in[6];
    const float* W2     = (const float*)d_in[7];
    const float* b2     = (const float*)d_in[8];

    const int M = in_sizes[2];
    const int E = in_sizes[3];

    float* out_bxyz = (float*)d_out;                 // [M][4]
    float* out_feat = out_bxyz + (size_t)M * 4;      // [M][64]
    float* W2T      = (float*)d_ws;                  // 16 KiB scratch

    w2_transpose_kernel<<<(COUT * COUT + 255) / 256, 256, 0, stream>>>(W2, W2T);

    gather_bxyz_kernel<<<(M + 255) / 256, 256, 0, stream>>>(
        (const float4*)bxyz, sidx, (float4*)out_bxyz, M);

    int n4 = M * COUT / 4;
    zero_feat_kernel<<<(n4 + 255) / 256, 256, 0, stream>>>((float4*)out_feat, n4);

    edge_kernel<<<(E + 255) / 256, 256, 0, stream>>>(
        (const float4*)bxyz, feat, e_pt, e_new, W1, b1, W2T, b2,
        (const float4*)out_bxyz, out_feat, E);
}

// Round 3
// 336.525 us; speedup vs baseline: 7.6698x; 5.6226x over previous
//
#include <hip/hip_runtime.h>

#define CIN 32
#define COUT 64
#define ITERS 4

typedef __attribute__((ext_vector_type(8))) short bf16x8;
typedef __attribute__((ext_vector_type(4))) float f32x4;

__device__ inline short bf16r(float x) {
    unsigned u = __float_as_uint(x);
    return (short)((u + 0x7FFFu + ((u >> 16) & 1u)) >> 16);
}

// ---------------------------------------------------------------------------
// Pack W1 (35x64, K zero-padded to 64) and W2 (64x64) into per-lane MFMA
// B-fragments for mfma_f32_16x16x32_bf16.
// Layout: wpack[f][lane][e], f = 0..7 -> W1 frag (kc = f>>2, nt = f&3),
//         f = 8..15 -> W2 frag. k = kc*32 + (lane>>4)*8 + e, n = nt*16 + (lane&15).
__global__ void pack_weights_kernel(const float* __restrict__ W1,
                                    const float* __restrict__ W2,
                                    short* __restrict__ wpack) {
    int t = blockIdx.x * blockDim.x + threadIdx.x;   // 16*64*8 = 8192
    if (t >= 16 * 64 * 8) return;
    int e = t & 7, l = (t >> 3) & 63, f = t >> 9;
    int g = l >> 4, n16 = l & 15;
    int kc = (f & 7) >> 2, nt = f & 3;
    int k = kc * 32 + g * 8 + e;
    int n = nt * 16 + n16;
    float v;
    if (f < 8) v = (k < CIN + 3) ? W1[k * COUT + n] : 0.f;
    else       v = W2[k * COUT + n];
    wpack[t] = bf16r(v);
}

// ---------------------------------------------------------------------------
__global__ void gather_bxyz_kernel(const float4* __restrict__ bxyz4,
                                   const int* __restrict__ sidx,
                                   float4* __restrict__ out4, int M) {
    int i = blockIdx.x * blockDim.x + threadIdx.x;
    if (i < M) out4[i] = bxyz4[sidx[i]];
}

__global__ void zero_feat_kernel(float4* __restrict__ p, int n4) {
    int i = blockIdx.x * blockDim.x + threadIdx.x;
    if (i < n4) p[i] = make_float4(0.f, 0.f, 0.f, 0.f);
}

// ---------------------------------------------------------------------------
// MFMA edge kernel: each wave processes 16 edges per iteration.
//   layer1: [16 x 64pad] x [64pad x 64] via 8 mfma_16x16x32_bf16
//           (K chunk 0 = feat cols 0..31, chunk 1 = rel xyz + zero pad)
//   layer1 -> layer2 operand transpose through wave-private LDS (XOR swizzle)
//   layer2: [16 x 64] x [64 x 64] via 8 mfma
//   scatter-max with clustered pre-check reads + atomicMax (relu => int cmp ok)
__global__ __launch_bounds__(256)
void edge_mfma_kernel(const float4* __restrict__ bxyz4,
                      const float* __restrict__ feat,
                      const int* __restrict__ e_point,
                      const int* __restrict__ e_new,
                      const bf16x8* __restrict__ wpack,   // [16][64] frags
                      const float* __restrict__ b1,
                      const float* __restrict__ b2,
                      const float4* __restrict__ new_bxyz4,
                      float* __restrict__ out_feat,       // [M][64] pre-zeroed
                      int E, int ntiles) {
    __shared__ float4 relbuf[4][16];      // per-wave: rel xyz + e_new bits
    __shared__ char   h1buf[4][2048];     // per-wave: 16 x 64 bf16, swizzled

    const int lane = threadIdx.x & 63;
    const int w    = threadIdx.x >> 6;
    const int m    = lane & 15;           // A-row / C-col index
    const int g    = lane >> 4;           // K/row group

    // --- weights -> VGPR B-fragments (once per wave) -----------------------
    bf16x8 w1b[8], w2b[8];
#pragma unroll
    for (int f = 0; f < 8; ++f) w1b[f] = wpack[f * 64 + lane];
#pragma unroll
    for (int f = 0; f < 8; ++f) w2b[f] = wpack[(8 + f) * 64 + lane];

    float b1v[4], b2v[4];
#pragma unroll
    for (int nt = 0; nt < 4; ++nt) {
        b1v[nt] = b1[nt * 16 + m];
        b2v[nt] = b2[nt * 16 + m];
    }

    char* h1p = h1buf[w];
    int*  outI = (int*)out_feat;

    for (int it = 0; it < ITERS; ++it) {
        int tile = (blockIdx.x * 4 + w) * ITERS + it;
        if (tile >= ntiles) break;                 // wave-uniform
        int ebase = tile * 16;

        // ---- gather: indices + A1 fragment (feat row chunk, 32B/lane) ----
        int eclamp = min(ebase + m, E - 1);
        int ep = e_point[eclamp];
        const float4* fp = (const float4*)(feat + (size_t)ep * CIN);
        float4 f0 = fp[g * 2];
        float4 f1 = fp[g * 2 + 1];

        if (g == 0) {
            int en0 = e_new[eclamp];
            float4 pb = bxyz4[ep];
            float4 nb = new_bxyz4[en0];
            relbuf[w][m] = make_float4(pb.y - nb.y, pb.z - nb.z, pb.w - nb.w,
                                       __int_as_float(en0));
        }

        bf16x8 a1;
        a1[0] = bf16r(f0.x); a1[1] = bf16r(f0.y); a1[2] = bf16r(f0.z); a1[3] = bf16r(f0.w);
        a1[4] = bf16r(f1.x); a1[5] = bf16r(f1.y); a1[6] = bf16r(f1.z); a1[7] = bf16r(f1.w);

        // rel -> A2 fragment (k = 32..34 live in group g==0, e<3)
        float4 rv = relbuf[w][m];
        bf16x8 a2 = {0, 0, 0, 0, 0, 0, 0, 0};
        if (g == 0) {
            a2[0] = bf16r(rv.x); a2[1] = bf16r(rv.y); a2[2] = bf16r(rv.z);
        }

        int enq[4];
#pragma unroll
        for (int q = 0; q < 4; ++q)
            enq[q] = __float_as_int(relbuf[w][g * 4 + q].w);

        // ---- layer 1 MFMA -------------------------------------------------
        f32x4 acc[4];
#pragma unroll
        for (int nt = 0; nt < 4; ++nt) {
            f32x4 c = {b1v[nt], b1v[nt], b1v[nt], b1v[nt]};
            c = __builtin_amdgcn_mfma_f32_16x16x32_bf16(a1, w1b[nt],     c, 0, 0, 0);
            c = __builtin_amdgcn_mfma_f32_16x16x32_bf16(a2, w1b[4 + nt], c, 0, 0, 0);
            acc[nt] = c;
        }

        // ---- relu + transpose via wave-private LDS (XOR swizzle) ---------
#pragma unroll
        for (int nt = 0; nt < 4; ++nt)
#pragma unroll
            for (int q = 0; q < 4; ++q) {
                int row = g * 4 + q;
                int col = m + nt * 16;
                float h = fmaxf(acc[nt][q], 0.f);
                int byte = (row * 128 + col * 2) ^ ((row & 7) << 4);
                *(short*)(h1p + byte) = bf16r(h);
            }

        bf16x8 a30 = *(const bf16x8*)(h1p + ((m * 128 + g * 16)       ^ ((m & 7) << 4)));
        bf16x8 a31 = *(const bf16x8*)(h1p + ((m * 128 + (4 + g) * 16) ^ ((m & 7) << 4)));

        // ---- layer 2 MFMA -------------------------------------------------
        f32x4 acc2[4];
#pragma unroll
        for (int nt = 0; nt < 4; ++nt) {
            f32x4 c = {b2v[nt], b2v[nt], b2v[nt], b2v[nt]};
            c = __builtin_amdgcn_mfma_f32_16x16x32_bf16(a30, w2b[nt],     c, 0, 0, 0);
            c = __builtin_amdgcn_mfma_f32_16x16x32_bf16(a31, w2b[4 + nt], c, 0, 0, 0);
            acc2[nt] = c;
        }

        // ---- scatter-max: clustered pre-check reads, then atomics --------
        int idxv[16], oldv[16];
#pragma unroll
        for (int nt = 0; nt < 4; ++nt)
#pragma unroll
            for (int q = 0; q < 4; ++q) {
                int idx = enq[q] * COUT + m + nt * 16;
                idxv[nt * 4 + q] = idx;
                oldv[nt * 4 + q] = outI[idx];
            }
#pragma unroll
        for (int nt = 0; nt < 4; ++nt)
#pragma unroll
            for (int q = 0; q < 4; ++q) {
                int row = g * 4 + q;
                if (ebase + row < E) {
                    float h = fmaxf(acc2[nt][q], 0.f);
                    int vb = __float_as_int(h);
                    if (vb > oldv[nt * 4 + q]) atomicMax(&outI[idxv[nt * 4 + q]], vb);
                }
            }
    }
}

// ---------------------------------------------------------------------------
extern "C" void kernel_launch(void* const* d_in, const int* in_sizes, int n_in,
                              void* d_out, int out_size, void* d_ws, size_t ws_size,
                              hipStream_t stream) {
    const float* bxyz   = (const float*)d_in[0];
    const float* feat   = (const float*)d_in[1];
    const int*   sidx   = (const int*)d_in[2];
    const int*   e_pt   = (const int*)d_in[3];
    const int*   e_new  = (const int*)d_in[4];
    const float* W1     = (const float*)d_in[5];
    const float* b1     = (const float*)d_in[6];
    const float* W2     = (const float*)d_in[7];
    const float* b2     = (const float*)d_in[8];

    const int M = in_sizes[2];
    const int E = in_sizes[3];

    float* out_bxyz = (float*)d_out;                 // [M][4]
    float* out_feat = out_bxyz + (size_t)M * 4;      // [M][64]
    short* wpack    = (short*)d_ws;                  // 16 KiB

    pack_weights_kernel<<<32, 256, 0, stream>>>(W1, W2, wpack);

    gather_bxyz_kernel<<<(M + 255) / 256, 256, 0, stream>>>(
        (const float4*)bxyz, sidx, (float4*)out_bxyz, M);

    int n4 = M * COUT / 4;
    zero_feat_kernel<<<(n4 + 255) / 256, 256, 0, stream>>>((float4*)out_feat, n4);

    int ntiles = (E + 15) / 16;
    int nblocks = (ntiles + 4 * ITERS - 1) / (4 * ITERS);
    edge_mfma_kernel<<<nblocks, 256, 0, stream>>>(
        (const float4*)bxyz, feat, e_pt, e_new,
        (const bf16x8*)wpack, b1, b2,
        (const float4*)out_bxyz, out_feat, E, ntiles);
}